// Round 3
// baseline (268.119 us; speedup 1.0000x reference)
//
#include <hip/hip_runtime.h>
#include <math.h>

// Problem constants (match reference)
#define B_    8
#define L_    2048
#define D_    1024
#define NN    64        // NUM_NODES
#define NH    8         // NUM_HEADS
#define NSLOT 512       // NN*NH
#define NTOK  (B_*L_)   // 16384
#define CAP   1024      // per-(b,node) entry list capacity (mean occupancy 64)
#define NCAND 6         // bf16 candidate count for fp32 rescore

typedef __attribute__((ext_vector_type(8))) short short8v;  // 8 bf16 (4 VGPRs)
typedef __attribute__((ext_vector_type(4))) float f32x4;    // MFMA accum

// ---------------- Kernel 1: bf16-MFMA logits GEMM with on-the-fly fp32->bf16
// vb[m][n] = bf16( sum_k x[m][k]*W[n][k] + bias[n] ),  m<16384, n<512, k<1024
// 128x128 block tile, BK=32, 4 waves (2x2, each 64x64 = 4x4 frags of 16x16x32).
// LDS tile [128 rows][4 slots of 8 bf16]; stored slot = slot ^ (row&3) so both
// ds_write_b128 and ds_read_b128 spread evenly over all 8 bank groups.
#define BM 128
#define BN 128
#define BK 32

__global__ __launch_bounds__(256) void k_gemm(const float* __restrict__ x,
                                              const float* __restrict__ W,
                                              const float* __restrict__ bias,
                                              ushort* __restrict__ vb) {
    __shared__ ushort As[2][BM * BK];
    __shared__ ushort Bs[2][BN * BK];

    const int tid  = threadIdx.x;
    const int lane = tid & 63;
    const int w    = tid >> 6;          // wave 0..3
    const int wr   = w >> 1, wc = w & 1;
    const int m0   = blockIdx.y * BM;
    const int n0   = blockIdx.x * BN;

    // staging: thread covers row = tid>>1 (0..127), k-half = (tid&1)*16
    const int srow = tid >> 1;
    const int skh  = (tid & 1) * 16;
    const float* xa = &x[(size_t)(m0 + srow) * D_ + skh];
    const float* wa = &W[(size_t)(n0 + srow) * D_ + skh];
    const int s0    = skh >> 3;                                   // base 8-elem slot
    const int wof0  = srow * 64 + (((s0 + 0) ^ (srow & 3)) << 4); // swizzled byte offs
    const int wof1  = srow * 64 + (((s0 + 1) ^ (srow & 3)) << 4);

    // fragment-read base byte offsets (swizzle: row&3 == lane&3 for all frags)
    const int slotsw = (((lane >> 4) ^ (lane & 3)) << 4);
    const int abase  = (wr * 64 + (lane & 15)) * 64 + slotsw;
    const int bbase  = (wc * 64 + (lane & 15)) * 64 + slotsw;

    f32x4 acc[4][4];
#pragma unroll
    for (int i = 0; i < 4; i++)
#pragma unroll
        for (int j = 0; j < 4; j++) acc[i][j] = (f32x4)(0.f);

    float4 ra[4], rb[4];
#pragma unroll
    for (int j = 0; j < 4; j++) {       // prefetch K-step 0
        ra[j] = *(const float4*)&xa[j * 4];
        rb[j] = *(const float4*)&wa[j * 4];
    }

    // pack two fp32 -> one u32 of two bf16 (truncation; rescore restores fp32 exactness)
    auto pk = [](float a, float b) {
        return (__float_as_uint(a) >> 16) | (__float_as_uint(b) & 0xFFFF0000u);
    };

    for (int t = 0; t < D_ / BK; t++) {
        __syncthreads();    // waves aligned; prior reads of this buffer are done
        uint4 pa0 = {pk(ra[0].x, ra[0].y), pk(ra[0].z, ra[0].w), pk(ra[1].x, ra[1].y), pk(ra[1].z, ra[1].w)};
        uint4 pa1 = {pk(ra[2].x, ra[2].y), pk(ra[2].z, ra[2].w), pk(ra[3].x, ra[3].y), pk(ra[3].z, ra[3].w)};
        uint4 pb0 = {pk(rb[0].x, rb[0].y), pk(rb[0].z, rb[0].w), pk(rb[1].x, rb[1].y), pk(rb[1].z, rb[1].w)};
        uint4 pb1 = {pk(rb[2].x, rb[2].y), pk(rb[2].z, rb[2].w), pk(rb[3].x, rb[3].y), pk(rb[3].z, rb[3].w)};
        char* Ab = (char*)As[t & 1];
        char* Bb = (char*)Bs[t & 1];
        *(uint4*)(Ab + wof0) = pa0;  *(uint4*)(Ab + wof1) = pa1;
        *(uint4*)(Bb + wof0) = pb0;  *(uint4*)(Bb + wof1) = pb1;
        if (t + 1 < D_ / BK) {       // issue next-step loads; hide HBM under MFMA
#pragma unroll
            for (int j = 0; j < 4; j++) {
                ra[j] = *(const float4*)&xa[(t + 1) * BK + j * 4];
                rb[j] = *(const float4*)&wa[(t + 1) * BK + j * 4];
            }
        }
        __syncthreads();    // LDS writes visible (barrier drains lgkm/vm)
        const char* Ar = (const char*)As[t & 1];
        const char* Br = (const char*)Bs[t & 1];
        short8v af[4], bf[4];
#pragma unroll
        for (int mi = 0; mi < 4; mi++) af[mi] = *(const short8v*)(Ar + abase + mi * 16 * 64);
#pragma unroll
        for (int ni = 0; ni < 4; ni++) bf[ni] = *(const short8v*)(Br + bbase + ni * 16 * 64);
#pragma unroll
        for (int mi = 0; mi < 4; mi++)
#pragma unroll
            for (int ni = 0; ni < 4; ni++)
                acc[mi][ni] = __builtin_amdgcn_mfma_f32_16x16x32_bf16(af[mi], bf[ni], acc[mi][ni], 0, 0, 0);
    }

    // epilogue: +bias, truncate to bf16, store
    // C/D layout (HW-verified): col = lane&15, row = (lane>>4)*4 + reg
#pragma unroll
    for (int ni = 0; ni < 4; ni++) {
        const int col = n0 + wc * 64 + ni * 16 + (lane & 15);
        const float bv = bias[col];
#pragma unroll
        for (int mi = 0; mi < 4; mi++) {
#pragma unroll
            for (int r = 0; r < 4; r++) {
                const int row = m0 + wr * 64 + mi * 16 + (lane >> 4) * 4 + r;
                vb[(size_t)row * NSLOT + col] = (ushort)(__float_as_uint(acc[mi][ni][r] + bv) >> 16);
            }
        }
    }
}

// ---------------- Kernel 2: per-token top-6 (bf16) -> fp32 rescore -> top-2 + lists
__global__ __launch_bounds__(256) void k_sel(const ushort* __restrict__ vb,
                                             const float* __restrict__ x,
                                             const float* __restrict__ W,
                                             const float* __restrict__ bias,
                                             float* __restrict__ vals,
                                             int* __restrict__ cnt,
                                             int* __restrict__ list) {
    const int lane = threadIdx.x & 63;
    const int wv   = threadIdx.x >> 6;
    const int t    = blockIdx.x * 4 + wv;   // token id
    const int base = lane * 8;

    // scan bf16 logits: one 16B load = 8 slots per lane
    uint4 c = *(const uint4*)(vb + (size_t)t * NSLOT + base);
    float lv[8];
    lv[0] = __uint_as_float((c.x & 0xFFFFu) << 16); lv[1] = __uint_as_float(c.x & 0xFFFF0000u);
    lv[2] = __uint_as_float((c.y & 0xFFFFu) << 16); lv[3] = __uint_as_float(c.y & 0xFFFF0000u);
    lv[4] = __uint_as_float((c.z & 0xFFFFu) << 16); lv[5] = __uint_as_float(c.z & 0xFFFF0000u);
    lv[6] = __uint_as_float((c.w & 0xFFFFu) << 16); lv[7] = __uint_as_float(c.w & 0xFFFF0000u);

    int cand[NCAND];
#pragma unroll
    for (int p = 0; p < NCAND; p++) {
        float bm = -INFINITY; int bi = 1 << 30;
#pragma unroll
        for (int j = 0; j < 8; j++)                 // strict > keeps lowest j on ties
            if (lv[j] > bm) { bm = lv[j]; bi = base + j; }
#pragma unroll
        for (int m = 1; m < 64; m <<= 1) {          // butterfly max, tie -> lower index
            float ov = __shfl_xor(bm, m, 64); int oi = __shfl_xor(bi, m, 64);
            if (ov > bm || (ov == bm && oi < bi)) { bm = ov; bi = oi; }
        }
        cand[p] = bi;                               // wave-uniform
#pragma unroll
        for (int j = 0; j < 8; j++)                 // exclude winner
            if (base + j == bi) lv[j] = -INFINITY;
    }

    // fp32 rescore of the 6 candidates (x row: 16 floats/lane; W rows L2-resident)
    float4 xv[4];
#pragma unroll
    for (int j = 0; j < 4; j++) xv[j] = *(const float4*)&x[(size_t)t * D_ + lane * 16 + j * 4];
    float rs[NCAND];
#pragma unroll
    for (int p = 0; p < NCAND; p++) {
        const float* wrow = &W[(size_t)cand[p] * D_ + lane * 16];
        float d = 0.f;
#pragma unroll
        for (int j = 0; j < 4; j++) {
            float4 wv4 = *(const float4*)&wrow[j * 4];
            d = fmaf(xv[j].x, wv4.x, d); d = fmaf(xv[j].y, wv4.y, d);
            d = fmaf(xv[j].z, wv4.z, d); d = fmaf(xv[j].w, wv4.w, d);
        }
#pragma unroll
        for (int m = 1; m < 64; m <<= 1) d += __shfl_xor(d, m, 64);
        rs[p] = d + bias[cand[p]];
    }

    // top-2 of 6 by fp32 value, tie -> lower slot index
    float v1 = -INFINITY, v2 = -INFINITY;
    int   i1 = 1 << 30,   i2 = 1 << 30;
#pragma unroll
    for (int p = 0; p < NCAND; p++) {
        const float nv = rs[p]; const int ni = cand[p];
        if (nv > v1 || (nv == v1 && ni < i1)) { v2 = v1; i2 = i1; v1 = nv; i1 = ni; }
        else if (nv > v2 || (nv == v2 && ni < i2)) { v2 = nv; i2 = ni; }
    }

    if (lane == 0) {
        vals[t * 2 + 0] = v1;
        vals[t * 2 + 1] = v2;
        const int b = t >> 11;
        const int l = t & (L_ - 1);
        int node = i1 >> 3, head = i1 & 7;
        int p = atomicAdd(&cnt[b * NN + node], 1);
        if (p < CAP) list[(size_t)(b * NN + node) * CAP + p] = (l << 4) | (head << 1) | 0;
        node = i2 >> 3; head = i2 & 7;
        p = atomicAdd(&cnt[b * NN + node], 1);
        if (p < CAP) list[(size_t)(b * NN + node) * CAP + p] = (l << 4) | (head << 1) | 1;
    }
}

// ---------------- Kernel 3: per-(b,node) gather-reduce; writes out + counts
__global__ __launch_bounds__(256) void k_scatter(const float* __restrict__ x,
                                                 const float* __restrict__ gv,
                                                 const float* __restrict__ vals,
                                                 const int* __restrict__ cnt,
                                                 const int* __restrict__ list,
                                                 float* __restrict__ out) {
    const int bn   = blockIdx.x;          // b*64 + node
    const int b    = bn >> 6;
    const int node = bn & 63;
    const int tid  = threadIdx.x;
    const int raw  = cnt[bn];
    const int n    = min(raw, CAP);

    __shared__ int   se[CAP];
    __shared__ float sv[CAP];
    __shared__ float sg[NH][D_];          // 32 KiB

    for (int i = tid; i < NH * D_; i += 256)
        sg[i >> 10][i & (D_ - 1)] = gv[((size_t)node << 13) + i];
    for (int i = tid; i < n; i += 256) {
        int e = list[(size_t)bn * CAP + i];
        se[i] = e;
        sv[i] = vals[(size_t)(((b << 11) | (e >> 4)) * 2 + (e & 1))];
    }
    __syncthreads();

    const int d = tid * 4;
    float ax = 0.f, ay = 0.f, az = 0.f, aw = 0.f;
    for (int i = 0; i < n; i++) {
        const int   e  = se[i];
        const float vv = sv[i];
        const int   l  = e >> 4;
        const int   h  = (e >> 1) & 7;
        float4 xv = *(const float4*)&x[(size_t)(((b << 11) | l) << 10) + d];
        float4 gh = *(const float4*)&sg[h][d];
        ax = fmaf(vv * xv.x, gh.x, ax);
        ay = fmaf(vv * xv.y, gh.y, ay);
        az = fmaf(vv * xv.z, gh.z, az);
        aw = fmaf(vv * xv.w, gh.w, aw);
    }
    float4 o = {ax, ay, az, aw};
    *(float4*)&out[((size_t)bn << 10) + d] = o;
    if (tid == 0) out[(size_t)B_ * NN * D_ + bn] = (float)raw;   // uncapped count
}

extern "C" void kernel_launch(void* const* d_in, const int* in_sizes, int n_in,
                              void* d_out, int out_size, void* d_ws, size_t ws_size,
                              hipStream_t stream) {
    (void)in_sizes; (void)n_in; (void)out_size; (void)ws_size;
    const float* x    = (const float*)d_in[0];
    const float* W    = (const float*)d_in[1];
    const float* bias = (const float*)d_in[2];
    const float* gv   = (const float*)d_in[3];
    float* out = (float*)d_out;

    // workspace layout (~18.2 MiB)
    ushort* vb  = (ushort*)d_ws;                       // 16384*512 bf16 = 16 MiB
    float* vals = (float*)(vb + (size_t)NTOK * NSLOT); // 32768 f32
    int*   cnt  = (int*)(vals + (size_t)NTOK * 2);     // 512 i32
    int*   list = cnt + B_ * NN;                       // 512*CAP i32 = 2 MiB

    hipMemsetAsync(cnt, 0, B_ * NN * sizeof(int), stream);

    dim3 g1(NSLOT / BN, NTOK / BM);                    // (4, 128)
    k_gemm<<<g1, 256, 0, stream>>>(x, W, bias, vb);
    k_sel<<<NTOK / 4, 256, 0, stream>>>(vb, x, W, bias, vals, cnt, list);
    k_scatter<<<B_ * NN, 256, 0, stream>>>(x, gv, vals, cnt, list, out);
}